// Round 14
// baseline (7841.676 us; speedup 1.0000x reference)
//
#include <hip/hip_runtime.h>

// ---------------------------------------------------------------------------
// SequenceTaggle: hierarchical GRU (sentence enc -> doc enc) on MI355X.
// V=32000 E=256 H=256 O=2 S=96 T=32 B=32, N = S*B = 3072.
// DEVICE DTYPES: float tensors f32; tokens int32; output f32.
// Internal: bf16 MFMA, f32 accumulation.
// pgru v10: weights STREAM from L2 every step (register-residency is
// impossible: allocator budget = 65536/threads, measured r7-r13). Pointer
// made opaque per-iteration so loads stay in the loop body and pipeline.
// 32 rows/WG (2 row-subtiles share each weight fragment -> half traffic).
// xw staged via global_load_lds, double-buffered, counted vmcnt(6).
// ---------------------------------------------------------------------------

typedef __bf16 bf16;
typedef __bf16 bf16x8 __attribute__((ext_vector_type(8)));
typedef __bf16 bf16x4 __attribute__((ext_vector_type(4)));
typedef float  f32x4  __attribute__((ext_vector_type(4)));

static __device__ __forceinline__ f32x4 mfma16(bf16x8 a, bf16x8 b, f32x4 c) {
  // A: lane row = lane&15, k = (lane>>4)*8 + j ; B: lane col = lane&15, same k
  // D: col = lane&15, row = (lane>>4)*4 + reg
  return __builtin_amdgcn_mfma_f32_16x16x32_bf16(a, b, c, 0, 0, 0);
}
static __device__ __forceinline__ float sigm(float x) { return 1.f / (1.f + __expf(-x)); }
// Raw barrier: LDS-visibility only; global loads/stores stay in flight.
static __device__ __forceinline__ void wg_barrier() {
  asm volatile("s_waitcnt lgkmcnt(0)" ::: "memory");
  __builtin_amdgcn_s_barrier();
  __builtin_amdgcn_sched_barrier(0);
}
// 16B global -> LDS DMA (LDS dest wave-uniform base + lane*16)
static __device__ __forceinline__ void gload16(const bf16* g, bf16* l) {
  __builtin_amdgcn_global_load_lds(
      (const __attribute__((address_space(1))) void*)g,
      (__attribute__((address_space(3))) void*)l, 16, 0, 0);
}

// ---- generic f32 -> bf16 (n4 float4 groups) ----
__global__ __launch_bounds__(256) void cvt_bf16(
    const float* __restrict__ s, bf16* __restrict__ d, int n4)
{
  int i = blockIdx.x * 256 + threadIdx.x;
  if (i < n4) {
    float4 v = ((const float4*)s)[i];
    bf16x4 o;
    o[0] = (bf16)v.x; o[1] = (bf16)v.y; o[2] = (bf16)v.z; o[3] = (bf16)v.w;
    ((bf16x4*)d)[i] = o;
  }
}

// ---- one-shot weight conversion: 12 GRU mats (196608 ea) + linW (131072) ----
__global__ __launch_bounds__(256) void conv13(
    const float* s0, const float* s1, const float* s2, const float* s3,
    const float* s4, const float* s5, const float* s6, const float* s7,
    const float* s8, const float* s9, const float* s10, const float* s11,
    const float* s12, bf16* __restrict__ dst)
{
  const float* srcs[13] = {s0,s1,s2,s3,s4,s5,s6,s7,s8,s9,s10,s11,s12};
  int m = blockIdx.y;
  int n4 = (m == 12) ? 32768 : 49152;
  int i = blockIdx.x * 256 + threadIdx.x;
  if (i >= n4) return;
  float4 v = ((const float4*)srcs[m])[i];
  bf16x4 o;
  o[0] = (bf16)v.x; o[1] = (bf16)v.y; o[2] = (bf16)v.z; o[3] = (bf16)v.w;
  ((bf16x4*)(dst + (size_t)m * 196608))[i] = o;
}

// ---- bmod[g][i] = bi[i] + (i<512 ? bh[i] : 0)  for 6 GRUs. grid (3,6). ----
__global__ __launch_bounds__(256) void prep_bias(
    const float* b0i, const float* b0h, const float* b1i, const float* b1h,
    const float* b2i, const float* b2h, const float* b3i, const float* b3h,
    const float* b4i, const float* b4h, const float* b5i, const float* b5h,
    float* __restrict__ out)
{
  const float* bis[6] = {b0i,b1i,b2i,b3i,b4i,b5i};
  const float* bhs[6] = {b0h,b1h,b2h,b3h,b4h,b5h};
  int g = blockIdx.y;
  int i = blockIdx.x * 256 + threadIdx.x;
  if (i < 768)
    out[g * 768 + i] = bis[g][i] + (i < 512 ? bhs[g][i] : 0.f);
}

// ---------------------------------------------------------------------------
// xw = X(M x 256) @ W(768 x 256)^T + bias -> (M x 768) bf16.
// Wave handles 64 rows x 16 cols (weight frags reused 4x). grid.x=(M/64)*12.
// ---------------------------------------------------------------------------
__global__ __launch_bounds__(256) void xw_gemm(
    const bf16* __restrict__ X,
    const bf16* __restrict__ W0, const float* __restrict__ b0, bf16* __restrict__ o0,
    const bf16* __restrict__ W1, const float* __restrict__ b1, bf16* __restrict__ o1)
{
  const bf16* W = blockIdx.y ? W1 : W0;
  const float* bias = blockIdx.y ? b1 : b0;
  bf16* out = blockIdx.y ? o1 : o0;
  int wave = (int)blockIdx.x * 4 + (threadIdx.x >> 6);
  int g64 = wave / 48, ct = wave - g64 * 48;
  int lane = threadIdx.x & 63;
  int r16 = lane & 15, g4 = lane >> 4;
  const bf16* wp = W + (size_t)(ct * 16 + r16) * 256;
  const bf16* xb = X + ((size_t)g64 * 64 + r16) * 256;
  f32x4 a0 = {0,0,0,0}, a1 = {0,0,0,0}, a2 = {0,0,0,0}, a3 = {0,0,0,0};
#pragma unroll
  for (int kk = 0; kk < 8; kk++) {
    int k0 = kk * 32 + g4 * 8;
    bf16x8 wf = *(const bf16x8*)(wp + k0);
    a0 = mfma16(*(const bf16x8*)(xb + k0), wf, a0);
    a1 = mfma16(*(const bf16x8*)(xb + 4096 + k0), wf, a1);
    a2 = mfma16(*(const bf16x8*)(xb + 8192 + k0), wf, a2);
    a3 = mfma16(*(const bf16x8*)(xb + 12288 + k0), wf, a3);
  }
  float bv = bias[ct * 16 + r16];
#pragma unroll
  for (int rt = 0; rt < 4; rt++) {
    f32x4 ac = rt == 0 ? a0 : rt == 1 ? a1 : rt == 2 ? a2 : a3;
#pragma unroll
    for (int j = 0; j < 4; j++)
      out[(size_t)(g64 * 64 + rt * 16 + g4 * 4 + j) * 768 + ct * 16 + r16] = (bf16)(ac[j] + bv);
  }
}

// ---------------------------------------------------------------------------
// xw1 = emb[tok] @ W^T + bias (gather fused). blockIdx.y = t.
// ---------------------------------------------------------------------------
__global__ __launch_bounds__(256) void xw_gather_gemm(
    const int* __restrict__ tok, const bf16* __restrict__ embb,
    const bf16* __restrict__ W, const float* __restrict__ bias,
    bf16* __restrict__ out, int c)
{
  int t = blockIdx.y;
  int wave = (int)blockIdx.x * 4 + (threadIdx.x >> 6);
  int g64 = wave / 48, ct = wave - g64 * 48;
  int lane = threadIdx.x & 63;
  int r16 = lane & 15, g4 = lane >> 4;
  const bf16* wp = W + (size_t)(ct * 16 + r16) * 256;
  const bf16* ap[4];
#pragma unroll
  for (int rt = 0; rt < 4; rt++) {
    int n = g64 * 64 + rt * 16 + r16;
    int tk = tok[((n >> 5) << 10) + (t << 5) + (n & 31)];
    ap[rt] = embb + (size_t)tk * 256;
  }
  f32x4 a0 = {0,0,0,0}, a1 = {0,0,0,0}, a2 = {0,0,0,0}, a3 = {0,0,0,0};
#pragma unroll
  for (int kk = 0; kk < 8; kk++) {
    int k0 = kk * 32 + g4 * 8;
    bf16x8 wf = *(const bf16x8*)(wp + k0);
    a0 = mfma16(*(const bf16x8*)(ap[0] + k0), wf, a0);
    a1 = mfma16(*(const bf16x8*)(ap[1] + k0), wf, a1);
    a2 = mfma16(*(const bf16x8*)(ap[2] + k0), wf, a2);
    a3 = mfma16(*(const bf16x8*)(ap[3] + k0), wf, a3);
  }
  float bv = bias[ct * 16 + r16];
#pragma unroll
  for (int rt = 0; rt < 4; rt++) {
    f32x4 ac = rt == 0 ? a0 : rt == 1 ? a1 : rt == 2 ? a2 : a3;
#pragma unroll
    for (int j = 0; j < 4; j++)
      out[((size_t)t * c + g64 * 64 + rt * 16 + g4 * 4 + j) * 768 + ct * 16 + r16] = (bf16)(ac[j] + bv);
  }
}

// ---------------------------------------------------------------------------
// Persistent GRU v10. 512 thr = 8 waves; wave w owns 32 cols (2 col-tiles);
// WG owns 32 batch rows (2 row-subtiles sharing every weight fragment).
// Weights STREAMED from L2 each step: wp made opaque per-iteration via asm
// so the 48 fragment loads live in the loop body and pipeline with MFMA.
// h (32x256) in LDS; xw staged via global_load_lds into per-wave regions
// xbuf[b][w][3][32][32], double-buffered, counted vmcnt(6).
// ---------------------------------------------------------------------------
__global__ __launch_bounds__(512)
void pgru(
    const bf16* __restrict__ xw0, const bf16* __restrict__ Wh0, const float* __restrict__ bh0,
    const bf16* __restrict__ xw1, const bf16* __restrict__ Wh1, const float* __restrict__ bh1,
    bf16* __restrict__ yout0, bf16* __restrict__ yout1, int ostride,
    const float* __restrict__ lng, const float* __restrict__ lnb,
    int steps, int Mtot, int rev0, int rev1)
{
  int dir = blockIdx.y;
  const bf16*  xw = dir ? xw1 : xw0;
  const bf16*  Wh = dir ? Wh1 : Wh0;
  const float* bh = dir ? bh1 : bh0;
  bf16* yout = dir ? yout1 : yout0;
  int rev = dir ? rev1 : rev0;

  __shared__ __align__(16) bf16 hbuf[32][280];          // 17,920 B
  __shared__ __align__(16) bf16 xbuf[2][8][3][32][32];  // 98,304 B -> ~116 KB

  int tid = threadIdx.x;
  int w = tid >> 6, lane = tid & 63, r16 = lane & 15, g4 = lane >> 4;
  int rowbase = (int)blockIdx.x * 32;
  int c0 = w * 32 + r16, c1 = c0 + 16;

  for (int i2 = tid; i2 < 1120; i2 += 512) ((bf16x8*)hbuf)[i2] = (bf16x8){};

  float bhn0 = bh[c0 + 512], bhn1 = bh[c1 + 512];

  // stage step st into xbuf[b][w]: 6 DMAs (2 per gate region [32][32]).
  int rr_ = lane >> 2;          // row within 16-row half
  int kc_ = (lane & 3) * 8;     // local col offset
  auto stage = [&](int b, int st) {
    const bf16* base = xw + ((size_t)st * Mtot + rowbase) * 768 + w * 32 + kc_;
#pragma unroll
    for (int g = 0; g < 3; g++) {
      gload16(base + (size_t)rr_ * 768 + g * 256,        &xbuf[b][w][g][0][0]);
      gload16(base + (size_t)(16 + rr_) * 768 + g * 256, &xbuf[b][w][g][16][0]);
    }
  };
  stage(0, rev ? steps - 1 : 0);
  wg_barrier();   // hbuf zero-init visible (xbuf readiness via vmcnt)

  for (int i = 0; i < steps; i++) {
    int cur = i & 1;
    int st = rev ? steps - 1 - i : i;
    if (i + 1 < steps) {
      stage(cur ^ 1, rev ? steps - 2 - i : i + 1);
      asm volatile("s_waitcnt vmcnt(6)" ::: "memory");   // my xbuf[cur] ready
    } else {
      asm volatile("s_waitcnt vmcnt(0)" ::: "memory");
    }
    __builtin_amdgcn_sched_barrier(0);

    // opaque weight pointers: loads cannot be hoisted out of the step loop
    const bf16* wp0 = Wh + (size_t)c0 * 256;
    const bf16* wp1 = Wh + (size_t)c1 * 256;
    asm volatile("" : "+v"(wp0), "+v"(wp1));

    f32x4 aR00={0,0,0,0}, aR01={0,0,0,0}, aR10={0,0,0,0}, aR11={0,0,0,0};
    f32x4 aZ00={0,0,0,0}, aZ01={0,0,0,0}, aZ10={0,0,0,0}, aZ11={0,0,0,0};
    f32x4 aN00={0,0,0,0}, aN01={0,0,0,0}, aN10={0,0,0,0}, aN11={0,0,0,0};
#pragma unroll
    for (int kk = 0; kk < 8; kk++) {
      int ko = kk * 32 + g4 * 8;
      bf16x8 wr0 = *(const bf16x8*)(wp0 + ko);
      bf16x8 wz0 = *(const bf16x8*)(wp0 + 65536 + ko);
      bf16x8 wn0 = *(const bf16x8*)(wp0 + 131072 + ko);
      bf16x8 wr1 = *(const bf16x8*)(wp1 + ko);
      bf16x8 wz1 = *(const bf16x8*)(wp1 + 65536 + ko);
      bf16x8 wn1 = *(const bf16x8*)(wp1 + 131072 + ko);
      bf16x8 a0 = *(const bf16x8*)&hbuf[r16][ko];        // rows 0-15
      bf16x8 a1 = *(const bf16x8*)&hbuf[16 + r16][ko];   // rows 16-31
      aR00 = mfma16(a0, wr0, aR00); aR01 = mfma16(a1, wr0, aR01);
      aZ00 = mfma16(a0, wz0, aZ00); aZ01 = mfma16(a1, wz0, aZ01);
      aN00 = mfma16(a0, wn0, aN00); aN01 = mfma16(a1, wn0, aN01);
      aR10 = mfma16(a0, wr1, aR10); aR11 = mfma16(a1, wr1, aR11);
      aZ10 = mfma16(a0, wz1, aZ10); aZ11 = mfma16(a1, wz1, aZ11);
      aN10 = mfma16(a0, wn1, aN10); aN11 = mfma16(a1, wn1, aN11);
    }

    float hn00[4], hn01[4], hn10[4], hn11[4];   // [colTile 0/1][rowSub 0/1]
#pragma unroll
    for (int j = 0; j < 4; j++) {
      int m0 = g4 * 4 + j, m1 = 16 + m0;
      { float r = sigm((float)xbuf[cur][w][0][m0][r16] + aR00[j]);
        float z = sigm((float)xbuf[cur][w][1][m0][r16] + aZ00[j]);
        float n = tanhf((float)xbuf[cur][w][2][m0][r16] + r * (aN00[j] + bhn0));
        hn00[j] = (1.f - z) * n + z * (float)hbuf[m0][c0]; }
      { float r = sigm((float)xbuf[cur][w][0][m1][r16] + aR01[j]);
        float z = sigm((float)xbuf[cur][w][1][m1][r16] + aZ01[j]);
        float n = tanhf((float)xbuf[cur][w][2][m1][r16] + r * (aN01[j] + bhn0));
        hn01[j] = (1.f - z) * n + z * (float)hbuf[m1][c0]; }
      { float r = sigm((float)xbuf[cur][w][0][m0][16 + r16] + aR10[j]);
        float z = sigm((float)xbuf[cur][w][1][m0][16 + r16] + aZ10[j]);
        float n = tanhf((float)xbuf[cur][w][2][m0][16 + r16] + r * (aN10[j] + bhn1));
        hn10[j] = (1.f - z) * n + z * (float)hbuf[m0][c1]; }
      { float r = sigm((float)xbuf[cur][w][0][m1][16 + r16] + aR11[j]);
        float z = sigm((float)xbuf[cur][w][1][m1][16 + r16] + aZ11[j]);
        float n = tanhf((float)xbuf[cur][w][2][m1][16 + r16] + r * (aN11[j] + bhn1));
        hn11[j] = (1.f - z) * n + z * (float)hbuf[m1][c1]; }
    }
    wg_barrier();                    // all hbuf / xbuf[cur] reads done WG-wide
#pragma unroll
    for (int j = 0; j < 4; j++) {
      int m0 = g4 * 4 + j, m1 = 16 + m0;
      hbuf[m0][c0] = (bf16)hn00[j];
      hbuf[m1][c0] = (bf16)hn01[j];
      hbuf[m0][c1] = (bf16)hn10[j];
      hbuf[m1][c1] = (bf16)hn11[j];
    }
    if (!lng) {
#pragma unroll
      for (int j = 0; j < 4; j++) {
        int m0 = g4 * 4 + j, m1 = 16 + m0;
        size_t r0 = ((size_t)st * Mtot + rowbase + m0) * ostride;
        size_t r1 = ((size_t)st * Mtot + rowbase + m1) * ostride;
        yout[r0 + c0] = (bf16)hn00[j];
        yout[r1 + c0] = (bf16)hn01[j];
        yout[r0 + c1] = (bf16)hn10[j];
        yout[r1 + c1] = (bf16)hn11[j];
      }
    }
    wg_barrier();                    // h_{i+1} visible
    if (lng) {
      // fused LN(256); recurrence keeps raw h. wave -> rows 4w..4w+3
#pragma unroll
      for (int rr = 0; rr < 4; rr++) {
        int r = w * 4 + rr;
        bf16x4 v4 = *(const bf16x4*)&hbuf[r][lane * 4];
        float v[4]; float sm = 0.f, sq = 0.f;
#pragma unroll
        for (int j = 0; j < 4; j++) { v[j] = (float)v4[j]; sm += v[j]; sq += v[j] * v[j]; }
        for (int msk = 32; msk; msk >>= 1) { sm += __shfl_xor(sm, msk); sq += __shfl_xor(sq, msk); }
        float mu  = sm * (1.f / 256.f);
        float var = sq * (1.f / 256.f) - mu * mu;
        float inv = rsqrtf(fmaxf(var, 0.f) + 1e-5f);
        bf16x4 o;
#pragma unroll
        for (int j = 0; j < 4; j++)
          o[j] = (bf16)((v[j] - mu) * inv * lng[lane * 4 + j] + lnb[lane * 4 + j]);
        *(bf16x4*)&yout[((size_t)st * Mtot + rowbase + r) * ostride + lane * 4] = o;
      }
    }
  }
}

// ---------------------------------------------------------------------------
// Sentence tail, t-parallel: block (r-tile, tg) accumulates 4 t's of
// tanh(LN512(hf||hb) @ linW^T + b) into part[tg] (f32). grid (c/16, 8).
// ---------------------------------------------------------------------------
__global__ __launch_bounds__(256) void sent_tail_part(
    const bf16* __restrict__ hf, const bf16* __restrict__ hb,
    const float* __restrict__ gam, const float* __restrict__ bet,
    const bf16* __restrict__ W, const float* __restrict__ bias,
    float* __restrict__ part, int c)
{
  int wave = threadIdx.x >> 6;
  int lane = threadIdx.x & 63;
  int r16 = lane & 15, g4 = lane >> 4;
  int r0 = (int)blockIdx.x << 4;
  int tg = blockIdx.y;
  size_t rowoff = (size_t)(r0 + r16) * 256;

  f32x4 ms0 = {0,0,0,0}, ms1 = {0,0,0,0}, ms2 = {0,0,0,0}, ms3 = {0,0,0,0};

  for (int tt = 0; tt < 4; tt++) {
    int t = tg * 4 + tt;
    const bf16* pf = hf + (size_t)t * c * 256 + rowoff;
    const bf16* pb = hb + (size_t)t * c * 256 + rowoff;
    bf16x8 xv[16];
    float s = 0.f, sq = 0.f;
#pragma unroll
    for (int kk = 0; kk < 16; kk++) {
      int k0 = kk * 32 + g4 * 8;
      xv[kk] = (kk < 8) ? *(const bf16x8*)(pf + k0) : *(const bf16x8*)(pb + k0 - 256);
#pragma unroll
      for (int j = 0; j < 8; j++) { float f = (float)xv[kk][j]; s += f; sq += f * f; }
    }
    s  += __shfl_xor(s, 16);  s  += __shfl_xor(s, 32);
    sq += __shfl_xor(sq, 16); sq += __shfl_xor(sq, 32);
    float mu  = s * (1.f / 512.f);
    float var = sq * (1.f / 512.f) - mu * mu;
    float inv = rsqrtf(fmaxf(var, 0.f) + 1e-5f);
#pragma unroll
    for (int kk = 0; kk < 16; kk++) {
      int k0 = kk * 32 + g4 * 8;
      float ga[8], be[8];
      *(float4*)(ga)     = *(const float4*)(gam + k0);
      *(float4*)(ga + 4) = *(const float4*)(gam + k0 + 4);
      *(float4*)(be)     = *(const float4*)(bet + k0);
      *(float4*)(be + 4) = *(const float4*)(bet + k0 + 4);
#pragma unroll
      for (int j = 0; j < 8; j++)
        xv[kk][j] = (bf16)(((float)xv[kk][j] - mu) * inv * ga[j] + be[j]);
    }
#pragma unroll
    for (int tc = 0; tc < 4; tc++) {
      int cj = wave * 64 + tc * 16;
      const bf16* wp = W + (size_t)(cj + r16) * 512;
      f32x4 acc = {0,0,0,0};
#pragma unroll
      for (int kk = 0; kk < 16; kk++)
        acc = mfma16(xv[kk], *(const bf16x8*)(wp + kk * 32 + g4 * 8), acc);
      float bb = bias[cj + r16];
      f32x4* msp = (tc == 0) ? &ms0 : (tc == 1) ? &ms1 : (tc == 2) ? &ms2 : &ms3;
#pragma unroll
      for (int j = 0; j < 4; j++) (*msp)[j] += tanhf(acc[j] + bb);
    }
  }
#pragma unroll
  for (int tc = 0; tc < 4; tc++) {
    int cj = wave * 64 + tc * 16;
    f32x4 ms = (tc == 0) ? ms0 : (tc == 1) ? ms1 : (tc == 2) ? ms2 : ms3;
#pragma unroll
    for (int j = 0; j < 4; j++)
      part[((size_t)tg * c + r0 + g4 * 4 + j) * 256 + cj + r16] = ms[j];
  }
}

// sum 8 partials, scale 1/32, write bf16. grid = c blocks x 256 thr.
__global__ __launch_bounds__(256) void tail_reduce(
    const float* __restrict__ part, bf16* __restrict__ out, int c)
{
  int idx = blockIdx.x * 256 + threadIdx.x;
  float s = 0.f;
#pragma unroll
  for (int g = 0; g < 8; g++) s += part[(size_t)g * c * 256 + idx];
  out[idx] = (bf16)(s * 0.03125f);
}

// ---------------------------------------------------------------------------
// Fused LN(512) + sigmoid head: out(3072x2 f32). Wave per row.
// ---------------------------------------------------------------------------
__global__ __launch_bounds__(256) void ln_out_head(
    const bf16* __restrict__ X, const float* __restrict__ lng, const float* __restrict__ lnb,
    const float* __restrict__ W, const float* __restrict__ bias, float* __restrict__ out)
{
  int w = threadIdx.x >> 6, lane = threadIdx.x & 63;
  int row = (int)blockIdx.x * 4 + w;
  bf16x8 v8 = *(const bf16x8*)&X[(size_t)row * 512 + lane * 8];
  float v[8]; float sm = 0.f, sq = 0.f;
#pragma unroll
  for (int j = 0; j < 8; j++) { v[j] = (float)v8[j]; sm += v[j]; sq += v[j] * v[j]; }
  for (int msk = 32; msk; msk >>= 1) { sm += __shfl_xor(sm, msk); sq += __shfl_xor(sq, msk); }
  float mu  = sm * (1.f / 512.f);
  float var = sq * (1.f / 512.f) - mu * mu;
  float inv = rsqrtf(fmaxf(var, 0.f) + 1e-5f);
  float a0 = 0.f, a1 = 0.f;
  int base = lane * 8;
#pragma unroll
  for (int j = 0; j < 8; j++) {
    float y = (v[j] - mu) * inv * lng[base + j] + lnb[base + j];
    a0 += y * W[base + j];
    a1 += y * W[512 + base + j];
  }
  for (int msk = 32; msk; msk >>= 1) { a0 += __shfl_xor(a0, msk); a1 += __shfl_xor(a1, msk); }
  if (lane == 0) {
    out[(size_t)row * 2 + 0] = sigm(a0 + bias[0]);
    out[(size_t)row * 2 + 1] = sigm(a1 + bias[1]);
  }
}

// ---------------------------------------------------------------------------
extern "C" void kernel_launch(void* const* d_in, const int* in_sizes, int n_in,
                              void* d_out, int out_size, void* d_ws, size_t ws_size,
                              hipStream_t stream)
{
  (void)in_sizes; (void)n_in; (void)out_size;
  const int*   tokens = (const int*)d_in[0];
  const float* emb    = (const float*)d_in[1];
  auto fp = [&](int i) { return (const float*)d_in[i]; };
  const float *s_WiF = fp(2),  *s_WhF = fp(3),  *s_biF = fp(4),  *s_bhF = fp(5);
  const float *s_lnF_g = fp(6), *s_lnF_b = fp(7);
  const float *s_Wi_f = fp(8),  *s_Wh_f = fp(9),  *s_bi_f = fp(10), *s_bh_f = fp(11);
  const float *s_Wi_b = fp(12), *s_Wh_b = fp(13), *s_bi_b = fp(14), *s_bh_b = fp(15);
  const float *s_ln_g = fp(16), *s_ln_b = fp(17), *s_linW = fp(18), *s_linb = fp(19);
  const float *dWiF = fp(20), *dWhF = fp(21), *dbiF = fp(22), *dbhF = fp(23);
  const float *d_lnF_g = fp(24), *d_lnF_b = fp(25);
  const float *dWi_f = fp(26), *dWh_f = fp(27), *dbi_f = fp(28), *dbh_f = fp(29);
  const float *dWi_b = fp(30), *dWh_b = fp(31), *dbi_b = fp(32), *dbh_b = fp(33);
  const float *d_ln_g = fp(34), *d_ln_b = fp(35), *out_W = fp(36), *out_b = fp(37);

  const int T = 32, S = 96;
  const int GW = 196608;

  // ---- converted bf16 weights + emb + folded biases ----
  bf16* wc = (bf16*)d_ws;
  bf16 *c_sWiF = wc,         *c_sWhF = wc + GW;
  bf16 *c_sWif = wc + 2*GW,  *c_sWhf = wc + 3*GW;
  bf16 *c_sWib = wc + 4*GW,  *c_sWhb = wc + 5*GW;
  bf16 *c_dWiF = wc + 6*GW,  *c_dWhF = wc + 7*GW;
  bf16 *c_dWif = wc + 8*GW,  *c_dWhf = wc + 9*GW;
  bf16 *c_dWib = wc + 10*GW, *c_dWhb = wc + 11*GW;
  bf16 *c_linW = wc + 12*GW;
  const size_t WB = (size_t)(12 * GW + 131072) * 2;       // 4,980,736
  bf16* embb = (bf16*)((char*)d_ws + WB);                 // 32000x256 bf16
  const size_t EB = (size_t)32000 * 256 * 2;              // 16,384,000
  float* bmod = (float*)((char*)d_ws + WB + EB);          // 6 x 768 f32
  const size_t BMB = 6 * 768 * 4;                         // 18,432

  conv13<<<dim3(192, 13), 256, 0, stream>>>(
      s_WiF, s_WhF, s_Wi_f, s_Wh_f, s_Wi_b, s_Wh_b,
      dWiF, dWhF, dWi_f, dWh_f, dWi_b, dWh_b, s_linW, wc);
  cvt_bf16<<<8000, 256, 0, stream>>>(emb, embb, 2048000);
  prep_bias<<<dim3(3, 6), 256, 0, stream>>>(
      s_biF, s_bhF, s_bi_f, s_bh_f, s_bi_b, s_bh_b,
      dbiF, dbhF, dbi_f, dbh_f, dbi_b, dbh_b, bmod);
  const float *bm_sF = bmod, *bm_sf = bmod + 768, *bm_sb = bmod + 1536;
  const float *bm_dF = bmod + 2304, *bm_df = bmod + 3072, *bm_db = bmod + 3840;

  // ---- fixed doc-side buffers ----
  char* ws = (char*)d_ws + WB + EB + BMB;
  bf16* store = (bf16*)ws;                           // (3072, 256)
  bf16* yd1ln = store + (size_t)3072 * 256;          // (3072, 256)
  bf16* ybid  = yd1ln + (size_t)3072 * 256;          // (3072, 512)
  bf16* xw_u  = ybid  + (size_t)3072 * 512;          // (3072, 768)
  bf16* xwdf  = xw_u  + (size_t)3072 * 768;
  bf16* xwdb  = xwdf  + (size_t)3072 * 768;
  const size_t fixedB = WB + EB + BMB
      + ((size_t)3072 * 256 * 2 + (size_t)3072 * 512 + (size_t)3 * 3072 * 768) * 2;

  // ---- sentence chunk size (rows; multiple of 64) ----
  // per-row: xw 49152 + y1ln 16384 + hf 16384 + hb 16384 = 98304 B
  int c = 3072;
  while (c > 192 && fixedB + (size_t)98304 * c > ws_size) c >>= 1;
  char* cb = (char*)d_ws + fixedB;
  bf16*  xw   = (bf16*)cb;                           // (T*c, 768), reused 3x
  bf16*  y1ln = (bf16*)(cb + (size_t)49152 * c);     // (T*c, 256)
  bf16*  hf   = (bf16*)(cb + (size_t)65536 * c);     // (T*c, 256)
  bf16*  hb   = (bf16*)(cb + (size_t)81920 * c);     // (T*c, 256)
  float* part = (float*)cb;                          // (8, c, 256) f32, alias xw

  // ---- sentence encoder, chunked ----
  for (int base = 0; base < 3072; base += c) {
    const int* tkb = tokens + (size_t)base * 32;
    xw_gather_gemm<<<dim3((c / 64) * 12, T), 256, 0, stream>>>(
        tkb, embb, c_sWiF, bm_sF, xw, c);
    pgru<<<dim3(c / 32, 1), 512, 0, stream>>>(
        xw, c_sWhF, s_bhF, nullptr, nullptr, nullptr,
        y1ln, nullptr, 256, s_lnF_g, s_lnF_b, T, c, 0, 0);
    xw_gemm<<<dim3((T * c / 64) * 12, 1), 256, 0, stream>>>(
        y1ln, c_sWif, bm_sf, xw, nullptr, nullptr, nullptr);
    pgru<<<dim3(c / 32, 1), 512, 0, stream>>>(
        xw, c_sWhf, s_bh_f, nullptr, nullptr, nullptr,
        hf, nullptr, 256, nullptr, nullptr, T, c, 0, 0);
    xw_gemm<<<dim3((T * c / 64) * 12, 1), 256, 0, stream>>>(
        y1ln, c_sWib, bm_sb, xw, nullptr, nullptr, nullptr);
    pgru<<<dim3(c / 32, 1), 512, 0, stream>>>(
        xw, c_sWhb, s_bh_b, nullptr, nullptr, nullptr,
        hb, nullptr, 256, nullptr, nullptr, T, c, 1, 0);
    sent_tail_part<<<dim3(c / 16, 8), 256, 0, stream>>>(
        hf, hb, s_ln_g, s_ln_b, c_linW, s_linb, part, c);
    tail_reduce<<<c, 256, 0, stream>>>(part, store + (size_t)base * 256, c);
  }

  // ---- document encoder ----
  xw_gemm<<<dim3((3072 / 64) * 12, 1), 256, 0, stream>>>(
      store, c_dWiF, bm_dF, xw_u, nullptr, nullptr, nullptr);
  pgru<<<dim3(1, 1), 512, 0, stream>>>(
      xw_u, c_dWhF, dbhF, nullptr, nullptr, nullptr,
      yd1ln, nullptr, 256, d_lnF_g, d_lnF_b, S, 32, 0, 0);
  xw_gemm<<<dim3((3072 / 64) * 12, 2), 256, 0, stream>>>(
      yd1ln, c_dWif, bm_df, xwdf, c_dWib, bm_db, xwdb);
  pgru<<<dim3(1, 2), 512, 0, stream>>>(
      xwdf, c_dWhf, dbh_f, xwdb, c_dWhb, dbh_b,
      ybid, ybid + 256, 512, nullptr, nullptr, S, 32, 0, 1);
  ln_out_head<<<768, 256, 0, stream>>>(ybid, d_ln_g, d_ln_b, out_W, out_b,
                                       (float*)d_out);
}

// Round 15
// 6153.695 us; speedup vs baseline: 1.2743x; 1.2743x over previous
//
#include <hip/hip_runtime.h>

// ---------------------------------------------------------------------------
// SequenceTaggle: hierarchical GRU (sentence enc -> doc enc) on MI355X.
// V=32000 E=256 H=256 O=2 S=96 T=32 B=32, N = S*B = 3072.
// DEVICE DTYPES: float tensors f32; tokens int32; output f32.
// Internal: bf16 MFMA, f32 accumulation.
// Allocator law (measured r7-r14): VGPR budget = 65536/threads. So:
//  - sentence recurrences: per-step hstep launches at 256 thr -> 256-VGPR
//    budget -> 96-VGPR weight slice stays register-resident, no spill.
//  - doc encoder: r12 persistent pgru (best known for tiny-batch case).
// ---------------------------------------------------------------------------

typedef __bf16 bf16;
typedef __bf16 bf16x8 __attribute__((ext_vector_type(8)));
typedef __bf16 bf16x4 __attribute__((ext_vector_type(4)));
typedef float  f32x4  __attribute__((ext_vector_type(4)));

static __device__ __forceinline__ f32x4 mfma16(bf16x8 a, bf16x8 b, f32x4 c) {
  // A: lane row = lane&15, k = (lane>>4)*8 + j ; B: lane col = lane&15, same k
  // D: col = lane&15, row = (lane>>4)*4 + reg
  return __builtin_amdgcn_mfma_f32_16x16x32_bf16(a, b, c, 0, 0, 0);
}
static __device__ __forceinline__ float sigm(float x) { return 1.f / (1.f + __expf(-x)); }
static __device__ __forceinline__ bf16x8 asbf(f32x4 v) {
  union { f32x4 f; bf16x8 b; } u; u.f = v; return u.b;
}
// Raw barrier: LDS-visibility only; global loads/stores stay in flight.
static __device__ __forceinline__ void wg_barrier() {
  asm volatile("s_waitcnt lgkmcnt(0)" ::: "memory");
  __builtin_amdgcn_s_barrier();
  __builtin_amdgcn_sched_barrier(0);
}
// 16B global -> LDS DMA (LDS dest wave-uniform base + lane*16)
static __device__ __forceinline__ void gload16(const bf16* g, bf16* l) {
  __builtin_amdgcn_global_load_lds(
      (const __attribute__((address_space(1))) void*)g,
      (__attribute__((address_space(3))) void*)l, 16, 0, 0);
}

// ---- generic f32 -> bf16 (n4 float4 groups) ----
__global__ __launch_bounds__(256) void cvt_bf16(
    const float* __restrict__ s, bf16* __restrict__ d, int n4)
{
  int i = blockIdx.x * 256 + threadIdx.x;
  if (i < n4) {
    float4 v = ((const float4*)s)[i];
    bf16x4 o;
    o[0] = (bf16)v.x; o[1] = (bf16)v.y; o[2] = (bf16)v.z; o[3] = (bf16)v.w;
    ((bf16x4*)d)[i] = o;
  }
}

// ---- one-shot weight conversion: 12 GRU mats (196608 ea) + linW (131072) ----
__global__ __launch_bounds__(256) void conv13(
    const float* s0, const float* s1, const float* s2, const float* s3,
    const float* s4, const float* s5, const float* s6, const float* s7,
    const float* s8, const float* s9, const float* s10, const float* s11,
    const float* s12, bf16* __restrict__ dst)
{
  const float* srcs[13] = {s0,s1,s2,s3,s4,s5,s6,s7,s8,s9,s10,s11,s12};
  int m = blockIdx.y;
  int n4 = (m == 12) ? 32768 : 49152;
  int i = blockIdx.x * 256 + threadIdx.x;
  if (i >= n4) return;
  float4 v = ((const float4*)srcs[m])[i];
  bf16x4 o;
  o[0] = (bf16)v.x; o[1] = (bf16)v.y; o[2] = (bf16)v.z; o[3] = (bf16)v.w;
  ((bf16x4*)(dst + (size_t)m * 196608))[i] = o;
}

// ---- bmod[g][i] = bi[i] + (i<512 ? bh[i] : 0)  for 6 GRUs. grid (3,6). ----
__global__ __launch_bounds__(256) void prep_bias(
    const float* b0i, const float* b0h, const float* b1i, const float* b1h,
    const float* b2i, const float* b2h, const float* b3i, const float* b3h,
    const float* b4i, const float* b4h, const float* b5i, const float* b5h,
    float* __restrict__ out)
{
  const float* bis[6] = {b0i,b1i,b2i,b3i,b4i,b5i};
  const float* bhs[6] = {b0h,b1h,b2h,b3h,b4h,b5h};
  int g = blockIdx.y;
  int i = blockIdx.x * 256 + threadIdx.x;
  if (i < 768)
    out[g * 768 + i] = bis[g][i] + (i < 512 ? bhs[g][i] : 0.f);
}

// ---------------------------------------------------------------------------
// xw = X(M x 256) @ W(768 x 256)^T + bias -> (M x 768) bf16.
// Wave handles 64 rows x 16 cols (weight frags reused 4x). grid.x=(M/64)*12.
// ---------------------------------------------------------------------------
__global__ __launch_bounds__(256) void xw_gemm(
    const bf16* __restrict__ X,
    const bf16* __restrict__ W0, const float* __restrict__ b0, bf16* __restrict__ o0,
    const bf16* __restrict__ W1, const float* __restrict__ b1, bf16* __restrict__ o1)
{
  const bf16* W = blockIdx.y ? W1 : W0;
  const float* bias = blockIdx.y ? b1 : b0;
  bf16* out = blockIdx.y ? o1 : o0;
  int wave = (int)blockIdx.x * 4 + (threadIdx.x >> 6);
  int g64 = wave / 48, ct = wave - g64 * 48;
  int lane = threadIdx.x & 63;
  int r16 = lane & 15, g4 = lane >> 4;
  const bf16* wp = W + (size_t)(ct * 16 + r16) * 256;
  const bf16* xb = X + ((size_t)g64 * 64 + r16) * 256;
  f32x4 a0 = {0,0,0,0}, a1 = {0,0,0,0}, a2 = {0,0,0,0}, a3 = {0,0,0,0};
#pragma unroll
  for (int kk = 0; kk < 8; kk++) {
    int k0 = kk * 32 + g4 * 8;
    bf16x8 wf = *(const bf16x8*)(wp + k0);
    a0 = mfma16(*(const bf16x8*)(xb + k0), wf, a0);
    a1 = mfma16(*(const bf16x8*)(xb + 4096 + k0), wf, a1);
    a2 = mfma16(*(const bf16x8*)(xb + 8192 + k0), wf, a2);
    a3 = mfma16(*(const bf16x8*)(xb + 12288 + k0), wf, a3);
  }
  float bv = bias[ct * 16 + r16];
#pragma unroll
  for (int rt = 0; rt < 4; rt++) {
    f32x4 ac = rt == 0 ? a0 : rt == 1 ? a1 : rt == 2 ? a2 : a3;
#pragma unroll
    for (int j = 0; j < 4; j++)
      out[(size_t)(g64 * 64 + rt * 16 + g4 * 4 + j) * 768 + ct * 16 + r16] = (bf16)(ac[j] + bv);
  }
}

// ---------------------------------------------------------------------------
// xw1 = emb[tok] @ W^T + bias (gather fused). blockIdx.y = t.
// ---------------------------------------------------------------------------
__global__ __launch_bounds__(256) void xw_gather_gemm(
    const int* __restrict__ tok, const bf16* __restrict__ embb,
    const bf16* __restrict__ W, const float* __restrict__ bias,
    bf16* __restrict__ out, int c)
{
  int t = blockIdx.y;
  int wave = (int)blockIdx.x * 4 + (threadIdx.x >> 6);
  int g64 = wave / 48, ct = wave - g64 * 48;
  int lane = threadIdx.x & 63;
  int r16 = lane & 15, g4 = lane >> 4;
  const bf16* wp = W + (size_t)(ct * 16 + r16) * 256;
  const bf16* ap[4];
#pragma unroll
  for (int rt = 0; rt < 4; rt++) {
    int n = g64 * 64 + rt * 16 + r16;
    int tk = tok[((n >> 5) << 10) + (t << 5) + (n & 31)];
    ap[rt] = embb + (size_t)tk * 256;
  }
  f32x4 a0 = {0,0,0,0}, a1 = {0,0,0,0}, a2 = {0,0,0,0}, a3 = {0,0,0,0};
#pragma unroll
  for (int kk = 0; kk < 8; kk++) {
    int k0 = kk * 32 + g4 * 8;
    bf16x8 wf = *(const bf16x8*)(wp + k0);
    a0 = mfma16(*(const bf16x8*)(ap[0] + k0), wf, a0);
    a1 = mfma16(*(const bf16x8*)(ap[1] + k0), wf, a1);
    a2 = mfma16(*(const bf16x8*)(ap[2] + k0), wf, a2);
    a3 = mfma16(*(const bf16x8*)(ap[3] + k0), wf, a3);
  }
  float bv = bias[ct * 16 + r16];
#pragma unroll
  for (int rt = 0; rt < 4; rt++) {
    f32x4 ac = rt == 0 ? a0 : rt == 1 ? a1 : rt == 2 ? a2 : a3;
#pragma unroll
    for (int j = 0; j < 4; j++)
      out[((size_t)t * c + g64 * 64 + rt * 16 + g4 * 4 + j) * 768 + ct * 16 + r16] = (bf16)(ac[j] + bv);
  }
}

// ---------------------------------------------------------------------------
// hstep: one GRU time step, h-recurrence only (xw = x@Wi + bi(+bh r/z)
// precomputed). 256 thr; wave = 64 rows x 16 out-cols; 24 weight frags =
// 96 VGPR register-resident (256-VGPR budget at 256 thr), reused 4x.
// grid.x = M/16 blocks. hp==null -> h_prev = 0.
// ---------------------------------------------------------------------------
__global__ __launch_bounds__(256) void hstep(
    const bf16* __restrict__ xw, const bf16* __restrict__ hp,
    bf16* __restrict__ ho, const bf16* __restrict__ Wh,
    const float* __restrict__ bh, int M)
{
  int wave = (int)blockIdx.x * 4 + (threadIdx.x >> 6);
  int rg = wave >> 4, ct = wave & 15;
  int lane = threadIdx.x & 63;
  int r16 = lane & 15, g4 = lane >> 4;
  int c = ct * 16 + r16;

  const bf16* wp = Wh + (size_t)c * 256;
  bf16x8 wr[8], wz[8], wn[8];
#pragma unroll
  for (int kk = 0; kk < 8; kk++) {
    int k0 = kk * 32 + g4 * 8;
    wr[kk] = *(const bf16x8*)(wp + k0);
    wz[kk] = *(const bf16x8*)(wp + 65536 + k0);
    wn[kk] = *(const bf16x8*)(wp + 131072 + k0);
  }
  float bhn = bh[c + 512];

#pragma unroll
  for (int rt = 0; rt < 4; rt++) {
    int rowb = rg * 64 + rt * 16;
    f32x4 aR = {0,0,0,0}, aZ = {0,0,0,0}, aN = {0,0,0,0};
    if (hp) {
      const bf16* ha = hp + (size_t)(rowb + r16) * 256;
#pragma unroll
      for (int kk = 0; kk < 8; kk++) {
        bf16x8 a = *(const bf16x8*)(ha + kk * 32 + g4 * 8);
        aR = mfma16(a, wr[kk], aR);
        aZ = mfma16(a, wz[kk], aZ);
        aN = mfma16(a, wn[kk], aN);
      }
    }
#pragma unroll
    for (int j = 0; j < 4; j++) {
      int row = rowb + g4 * 4 + j;
      const bf16* xq = xw + (size_t)row * 768 + c;
      float r = sigm((float)xq[0]   + aR[j]);
      float z = sigm((float)xq[256] + aZ[j]);
      float n = tanhf((float)xq[512] + r * (aN[j] + bhn));
      float hpv = hp ? (float)hp[(size_t)row * 256 + c] : 0.f;
      ho[(size_t)row * 256 + c] = (bf16)((1.f - z) * n + z * hpv);
    }
  }
  (void)M;
}

// ---------------------------------------------------------------------------
// Row LayerNorm in place (bf16 data, f32 params), wave per row, D=256.
// ---------------------------------------------------------------------------
__global__ __launch_bounds__(256) void ln_rows(
    bf16* __restrict__ data, const float* __restrict__ gam, const float* __restrict__ bet,
    int rows)
{
  int wid = threadIdx.x >> 6, lane = threadIdx.x & 63;
  int row = (blockIdx.x << 2) + wid;
  if (row >= rows) return;
  bf16* p = data + (size_t)row * 256;
  bf16x4 t4 = *(const bf16x4*)(p + lane * 4);
  float v[4]; float s = 0.f, sq = 0.f;
#pragma unroll
  for (int j = 0; j < 4; j++) { v[j] = (float)t4[j]; s += v[j]; sq += v[j] * v[j]; }
  for (int m = 32; m; m >>= 1) { s += __shfl_xor(s, m); sq += __shfl_xor(sq, m); }
  float mu  = s * (1.f / 256.f);
  float var = sq * (1.f / 256.f) - mu * mu;
  float inv = rsqrtf(fmaxf(var, 0.f) + 1e-5f);
  bf16x4 o;
#pragma unroll
  for (int j = 0; j < 4; j++)
    o[j] = (bf16)((v[j] - mu) * inv * gam[lane * 4 + j] + bet[lane * 4 + j]);
  *(bf16x4*)(p + lane * 4) = o;
}

// ---------------------------------------------------------------------------
// Persistent GRU (r12 version, doc encoder only). 512 thr = 8 waves; wave
// owns 32 cols. Static LDS 82.7 KB; xw via global_load_lds, vmcnt(3).
// ---------------------------------------------------------------------------
__global__ __launch_bounds__(512)
__attribute__((amdgpu_waves_per_eu(1, 2)))
void pgru(
    const bf16* __restrict__ xw0, const bf16* __restrict__ Wh0, const float* __restrict__ bh0,
    const bf16* __restrict__ xw1, const bf16* __restrict__ Wh1, const float* __restrict__ bh1,
    bf16* __restrict__ yout0, bf16* __restrict__ yout1, int ostride,
    const float* __restrict__ lng, const float* __restrict__ lnb,
    int steps, int Mtot, int rev0, int rev1)
{
  int dir = blockIdx.y;
  const bf16*  xw = dir ? xw1 : xw0;
  const bf16*  Wh = dir ? Wh1 : Wh0;
  const float* bh = dir ? bh1 : bh0;
  bf16* yout = dir ? yout1 : yout0;
  int rev = dir ? rev1 : rev0;

  __shared__ __align__(16) bf16 hbuf[16][280];
  __shared__ __align__(16) bf16 xbuf[3][8][3][16][32];

  int tid = threadIdx.x;
  int w = tid >> 6, lane = tid & 63, r16 = lane & 15, g4 = lane >> 4;
  int rowbase = (int)blockIdx.x * 16;
  int c0 = w * 32 + r16, c1 = c0 + 16;

  for (int i2 = tid; i2 < 560; i2 += 512) ((bf16x8*)hbuf)[i2] = (bf16x8){};

  f32x4 wr0[8], wz0[8], wn0[8], wr1[8], wz1[8], wn1[8];
  {
    const bf16* W0 = Wh + (size_t)c0 * 256;
    const bf16* W1 = Wh + (size_t)c1 * 256;
#pragma unroll
    for (int kk = 0; kk < 8; kk++) {
      int k0 = kk * 32 + g4 * 8;
      wr0[kk] = *(const f32x4*)(W0 + k0);          asm volatile("" : "+v"(wr0[kk]));
      wz0[kk] = *(const f32x4*)(W0 + 65536 + k0);  asm volatile("" : "+v"(wz0[kk]));
      wn0[kk] = *(const f32x4*)(W0 + 131072 + k0); asm volatile("" : "+v"(wn0[kk]));
      wr1[kk] = *(const f32x4*)(W1 + k0);          asm volatile("" : "+v"(wr1[kk]));
      wz1[kk] = *(const f32x4*)(W1 + 65536 + k0);  asm volatile("" : "+v"(wz1[kk]));
      wn1[kk] = *(const f32x4*)(W1 + 131072 + k0); asm volatile("" : "+v"(wn1[kk]));
    }
  }
  float bhn0 = bh[c0 + 512], bhn1 = bh[c1 + 512];

  int m_ = lane >> 2;
  int k_ = (lane & 3) * 8;
  auto stage = [&](int b, int st) {
    const bf16* s = xw + ((size_t)st * Mtot + rowbase + m_) * 768 + w * 32 + k_;
    gload16(s,       &xbuf[b][w][0][0][0]);
    gload16(s + 256, &xbuf[b][w][1][0][0]);
    gload16(s + 512, &xbuf[b][w][2][0][0]);
  };
  stage(0, rev ? steps - 1 : 0);
  wg_barrier();

  for (int i = 0; i < steps; i++) {
    int cur = i % 3;
    int st = rev ? steps - 1 - i : i;
    if (i + 1 < steps) {
      stage((i + 1) % 3, rev ? steps - 2 - i : i + 1);
      asm volatile("s_waitcnt vmcnt(3)" ::: "memory");
    } else {
      asm volatile("s_waitcnt vmcnt(0)" ::: "memory");
    }
    __builtin_amdgcn_sched_barrier(0);

    float hn0[4], hn1[4];
    {
      f32x4 a0 = {0,0,0,0}, a1 = {0,0,0,0}, a2 = {0,0,0,0};
#pragma unroll
      for (int kk = 0; kk < 8; kk++) {
        bf16x8 a = *(const bf16x8*)&hbuf[r16][kk * 32 + g4 * 8];
        a0 = mfma16(a, asbf(wr0[kk]), a0);
        a1 = mfma16(a, asbf(wz0[kk]), a1);
        a2 = mfma16(a, asbf(wn0[kk]), a2);
      }
#pragma unroll
      for (int j = 0; j < 4; j++) {
        int m = g4 * 4 + j;
        float r = sigm((float)xbuf[cur][w][0][m][r16] + a0[j]);
        float z = sigm((float)xbuf[cur][w][1][m][r16] + a1[j]);
        float n = tanhf((float)xbuf[cur][w][2][m][r16] + r * (a2[j] + bhn0));
        hn0[j] = (1.f - z) * n + z * (float)hbuf[m][c0];
      }
    }
    {
      f32x4 a0 = {0,0,0,0}, a1 = {0,0,0,0}, a2 = {0,0,0,0};
#pragma unroll
      for (int kk = 0; kk < 8; kk++) {
        bf16x8 a = *(const bf16x8*)&hbuf[r16][kk * 32 + g4 * 8];
        a0 = mfma16(a, asbf(wr1[kk]), a0);
        a1 = mfma16(a, asbf(wz1[kk]), a1);
        a2 = mfma16(a, asbf(wn1[kk]), a2);
      }
#pragma unroll
      for (int j = 0; j < 4; j++) {
        int m = g4 * 4 + j;
        float r = sigm((float)xbuf[cur][w][0][m][r16 + 16] + a0[j]);
        float z = sigm((float)xbuf[cur][w][1][m][r16 + 16] + a1[j]);
        float n = tanhf((float)xbuf[cur][w][2][m][r16 + 16] + r * (a2[j] + bhn1));
        hn1[j] = (1.f - z) * n + z * (float)hbuf[m][c1];
      }
    }
    wg_barrier();
#pragma unroll
    for (int j = 0; j < 4; j++) {
      int m = g4 * 4 + j;
      hbuf[m][c0] = (bf16)hn0[j];
      hbuf[m][c1] = (bf16)hn1[j];
    }
    if (!lng) {
#pragma unroll
      for (int j = 0; j < 4; j++) {
        size_t ro = ((size_t)st * Mtot + rowbase + g4 * 4 + j) * ostride;
        yout[ro + c0] = (bf16)hn0[j];
        yout[ro + c1] = (bf16)hn1[j];
      }
    }
    wg_barrier();
    if (lng) {
#pragma unroll
      for (int rr = 0; rr < 2; rr++) {
        int r = w * 2 + rr;
        bf16x4 v4 = *(const bf16x4*)&hbuf[r][lane * 4];
        float v[4]; float sm = 0.f, sq = 0.f;
#pragma unroll
        for (int j = 0; j < 4; j++) { v[j] = (float)v4[j]; sm += v[j]; sq += v[j] * v[j]; }
        for (int msk = 32; msk; msk >>= 1) { sm += __shfl_xor(sm, msk); sq += __shfl_xor(sq, msk); }
        float mu  = sm * (1.f / 256.f);
        float var = sq * (1.f / 256.f) - mu * mu;
        float inv = rsqrtf(fmaxf(var, 0.f) + 1e-5f);
        bf16x4 o;
#pragma unroll
        for (int j = 0; j < 4; j++)
          o[j] = (bf16)((v[j] - mu) * inv * lng[lane * 4 + j] + lnb[lane * 4 + j]);
        *(bf16x4*)&yout[((size_t)st * Mtot + rowbase + r) * ostride + lane * 4] = o;
      }
    }
  }
}

// ---------------------------------------------------------------------------
// Sentence tail, t-parallel: block (r-tile, tg) accumulates 4 t's of
// tanh(LN512(hf||hb) @ linW^T + b) into part[tg] (f32). grid (c/16, 8).
// ---------------------------------------------------------------------------
__global__ __launch_bounds__(256) void sent_tail_part(
    const bf16* __restrict__ hf, const bf16* __restrict__ hb,
    const float* __restrict__ gam, const float* __restrict__ bet,
    const bf16* __restrict__ W, const float* __restrict__ bias,
    float* __restrict__ part, int c)
{
  int wave = threadIdx.x >> 6;
  int lane = threadIdx.x & 63;
  int r16 = lane & 15, g4 = lane >> 4;
  int r0 = (int)blockIdx.x << 4;
  int tg = blockIdx.y;
  size_t rowoff = (size_t)(r0 + r16) * 256;

  f32x4 ms0 = {0,0,0,0}, ms1 = {0,0,0,0}, ms2 = {0,0,0,0}, ms3 = {0,0,0,0};

  for (int tt = 0; tt < 4; tt++) {
    int t = tg * 4 + tt;
    const bf16* pf = hf + (size_t)t * c * 256 + rowoff;
    const bf16* pb = hb + (size_t)t * c * 256 + rowoff;
    bf16x8 xv[16];
    float s = 0.f, sq = 0.f;
#pragma unroll
    for (int kk = 0; kk < 16; kk++) {
      int k0 = kk * 32 + g4 * 8;
      xv[kk] = (kk < 8) ? *(const bf16x8*)(pf + k0) : *(const bf16x8*)(pb + k0 - 256);
#pragma unroll
      for (int j = 0; j < 8; j++) { float f = (float)xv[kk][j]; s += f; sq += f * f; }
    }
    s  += __shfl_xor(s, 16);  s  += __shfl_xor(s, 32);
    sq += __shfl_xor(sq, 16); sq += __shfl_xor(sq, 32);
    float mu  = s * (1.f / 512.f);
    float var = sq * (1.f / 512.f) - mu * mu;
    float inv = rsqrtf(fmaxf(var, 0.f) + 1e-5f);
#pragma unroll
    for (int kk = 0; kk < 16; kk++) {
      int k0 = kk * 32 + g4 * 8;
      float ga[8], be[8];
      *(float4*)(ga)     = *(const float4*)(gam + k0);
      *(float4*)(ga + 4) = *(const float4*)(gam + k0 + 4);
      *(float4*)(be)     = *(const float4*)(bet + k0);
      *(float4*)(be + 4) = *(const float4*)(bet + k0 + 4);
#pragma unroll
      for (int j = 0; j < 8; j++)
        xv[kk][j] = (bf16)(((float)xv[kk][j] - mu) * inv * ga[j] + be[j]);
    }
#pragma unroll
    for (int tc = 0; tc < 4; tc++) {
      int cj = wave * 64 + tc * 16;
      const bf16* wp = W + (size_t)(cj + r16) * 512;
      f32x4 acc = {0,0,0,0};
#pragma unroll
      for (int kk = 0; kk < 16; kk++)
        acc = mfma16(xv[kk], *(const bf16x8*)(wp + kk * 32 + g4 * 8), acc);
      float bb = bias[cj + r16];
      f32x4* msp = (tc == 0) ? &ms0 : (tc == 1) ? &ms1 : (tc == 2) ? &ms2 : &ms3;
#pragma unroll
      for (int j = 0; j < 4; j++) (*msp)[j] += tanhf(acc[j] + bb);
    }
  }
#pragma unroll
  for (int tc = 0; tc < 4; tc++) {
    int cj = wave * 64 + tc * 16;
    f32x4 ms = (tc == 0) ? ms0 : (tc == 1) ? ms1 : (tc == 2) ? ms2 : ms3;
#pragma unroll
    for (int j = 0; j < 4; j++)
      part[((size_t)tg * c + r0 + g4 * 4 + j) * 256 + cj + r16] = ms[j];
  }
}

// sum 8 partials, scale 1/32, write bf16. grid = c blocks x 256 thr.
__global__ __launch_bounds__(256) void tail_reduce(
    const float* __restrict__ part, bf16* __restrict__ out, int c)
{
  int idx = blockIdx.x * 256 + threadIdx.x;
  float s = 0.f;
#pragma unroll
  for (int g = 0; g < 8; g++) s += part[(size_t)g * c * 256 + idx];
  out[idx] = (bf16)(s * 0.03125f);
}

// ---------------------------------------------------------------------------
// Fused LN(512) + sigmoid head: out(3072x2 f32). Wave per row.
// ---------------------------------------------------------------------------
__global__ __launch_bounds__(256) void ln_out_head(
    const bf16* __restrict__ X, const float* __restrict__ lng, const float* __restrict__ lnb,
    const float* __restrict__ W, const float* __restrict__ bias, float* __restrict__ out)
{
  int w = threadIdx.x >> 6, lane = threadIdx.x & 63;
  int row = (int)blockIdx.x * 4 + w;
  bf16x8 v8 = *(const bf16x8*)&X[(size_t)row * 512 + lane * 8];
  float v[8]; float sm = 0.f, sq = 0.f;
#pragma unroll
  for (int j = 0; j < 8; j++) { v[j] = (float)v8[j]; sm += v[j]; sq += v[j] * v[j]; }
  for (int msk = 32; msk; msk >>= 1) { sm += __shfl_xor(sm, msk); sq += __shfl_xor(sq, msk); }
  float mu  = sm * (1.f / 512.f);
  float var = sq * (1.f / 512.f) - mu * mu;
  float inv = rsqrtf(fmaxf(var, 0.f) + 1e-5f);
  float a0 = 0.f, a1 = 0.f;
  int base = lane * 8;
#pragma unroll
  for (int j = 0; j < 8; j++) {
    float y = (v[j] - mu) * inv * lng[base + j] + lnb[base + j];
    a0 += y * W[base + j];
    a1 += y * W[512 + base + j];
  }
  for (int msk = 32; msk; msk >>= 1) { a0 += __shfl_xor(a0, msk); a1 += __shfl_xor(a1, msk); }
  if (lane == 0) {
    out[(size_t)row * 2 + 0] = sigm(a0 + bias[0]);
    out[(size_t)row * 2 + 1] = sigm(a1 + bias[1]);
  }
}

// ---------------------------------------------------------------------------
extern "C" void kernel_launch(void* const* d_in, const int* in_sizes, int n_in,
                              void* d_out, int out_size, void* d_ws, size_t ws_size,
                              hipStream_t stream)
{
  (void)in_sizes; (void)n_in; (void)out_size;
  const int*   tokens = (const int*)d_in[0];
  const float* emb    = (const float*)d_in[1];
  auto fp = [&](int i) { return (const float*)d_in[i]; };
  const float *s_WiF = fp(2),  *s_WhF = fp(3),  *s_biF = fp(4),  *s_bhF = fp(5);
  const float *s_lnF_g = fp(6), *s_lnF_b = fp(7);
  const float *s_Wi_f = fp(8),  *s_Wh_f = fp(9),  *s_bi_f = fp(10), *s_bh_f = fp(11);
  const float *s_Wi_b = fp(12), *s_Wh_b = fp(13), *s_bi_b = fp(14), *s_bh_b = fp(15);
  const float *s_ln_g = fp(16), *s_ln_b = fp(17), *s_linW = fp(18), *s_linb = fp(19);
  const float *dWiF = fp(20), *dWhF = fp(21), *dbiF = fp(22), *dbhF = fp(23);
  const float *d_lnF_g = fp(24), *d_lnF_b = fp(25);
  const float *dWi_f = fp(26), *dWh_f = fp(27), *dbi_f = fp(28), *dbh_f = fp(29);
  const float *dWi_b = fp(30), *dWh_b = fp(31), *dbi_b = fp(32), *dbh_b = fp(33);
  const float *d_ln_g = fp(34), *d_ln_b = fp(35), *out_W = fp(36), *out_b = fp(37);

  const int T = 32, S = 96;
  const int GW = 196608;

  // ---- converted bf16 weights + emb + folded biases ----
  bf16* wc = (bf16*)d_ws;
  bf16 *c_sWiF = wc,         *c_sWhF = wc + GW;
  bf16 *c_sWif = wc + 2*GW,  *c_sWhf = wc + 3*GW;
  bf16 *c_sWib = wc + 4*GW,  *c_sWhb = wc + 5*GW;
  bf16 *c_dWiF = wc + 6*GW,  *c_dWhF = wc + 7*GW;
  bf16 *c_dWif = wc + 8*GW,  *c_dWhf = wc + 9*GW;
  bf16 *c_dWib = wc + 10*GW, *c_dWhb = wc + 11*GW;
  bf16 *c_linW = wc + 12*GW;
  const size_t WB = (size_t)(12 * GW + 131072) * 2;       // 4,980,736
  bf16* embb = (bf16*)((char*)d_ws + WB);                 // 32000x256 bf16
  const size_t EB = (size_t)32000 * 256 * 2;              // 16,384,000
  float* bmod = (float*)((char*)d_ws + WB + EB);          // 6 x 768 f32
  const size_t BMB = 6 * 768 * 4;                         // 18,432

  conv13<<<dim3(192, 13), 256, 0, stream>>>(
      s_WiF, s_WhF, s_Wi_f, s_Wh_f, s_Wi_b, s_Wh_b,
      dWiF, dWhF, dWi_f, dWh_f, dWi_b, dWh_b, s_linW, wc);
  cvt_bf16<<<8000, 256, 0, stream>>>(emb, embb, 2048000);
  prep_bias<<<dim3(3, 6), 256, 0, stream>>>(
      s_biF, s_bhF, s_bi_f, s_bh_f, s_bi_b, s_bh_b,
      dbiF, dbhF, dbi_f, dbh_f, dbi_b, dbh_b, bmod);
  const float *bm_sF = bmod, *bm_sf = bmod + 768, *bm_sb = bmod + 1536;
  const float *bm_dF = bmod + 2304, *bm_df = bmod + 3072, *bm_db = bmod + 3840;

  // ---- fixed doc-side buffers ----
  char* ws = (char*)d_ws + WB + EB + BMB;
  bf16* store = (bf16*)ws;                           // (3072, 256)
  bf16* yd1ln = store + (size_t)3072 * 256;          // (3072, 256)
  bf16* ybid  = yd1ln + (size_t)3072 * 256;          // (3072, 512)
  bf16* xw_u  = ybid  + (size_t)3072 * 512;          // (3072, 768)
  bf16* xwdf  = xw_u  + (size_t)3072 * 768;
  bf16* xwdb  = xwdf  + (size_t)3072 * 768;
  const size_t fixedB = WB + EB + BMB
      + ((size_t)3072 * 256 * 2 + (size_t)3072 * 512 + (size_t)3 * 3072 * 768) * 2;

  // ---- sentence chunk size (rows; multiple of 64) ----
  // per-row: xw 49152 + y1 16384 + hf 16384 + hb 16384 = 98304 B
  int c = 3072;
  while (c > 192 && fixedB + (size_t)98304 * c > ws_size) c >>= 1;
  char* cb = (char*)d_ws + fixedB;
  bf16*  xw = (bf16*)cb;                             // (T*c, 768), reused 3x
  bf16*  y1 = (bf16*)(cb + (size_t)49152 * c);       // (T*c, 256) raw h -> LN'd in place
  bf16*  hf = (bf16*)(cb + (size_t)65536 * c);       // (T*c, 256)
  bf16*  hb = (bf16*)(cb + (size_t)81920 * c);       // (T*c, 256)
  float* part = (float*)cb;                          // (8, c, 256) f32, alias xw

  const size_t cH = (size_t)c * 256;
  const size_t cX = (size_t)c * 768;

  // ---- sentence encoder, chunked ----
  for (int base = 0; base < 3072; base += c) {
    const int* tkb = tokens + (size_t)base * 32;
    // GRU1: x-projection (emb gather fused), then per-step recurrence
    xw_gather_gemm<<<dim3((c / 64) * 12, T), 256, 0, stream>>>(
        tkb, embb, c_sWiF, bm_sF, xw, c);
    for (int t = 0; t < T; t++)
      hstep<<<c / 16, 256, 0, stream>>>(
          xw + (size_t)t * cX, t ? y1 + (size_t)(t - 1) * cH : nullptr,
          y1 + (size_t)t * cH, c_sWhF, s_bhF, c);
    ln_rows<<<(T * c) / 4, 256, 0, stream>>>(y1, s_lnF_g, s_lnF_b, T * c);
    // bi forward
    xw_gemm<<<dim3((T * c / 64) * 12, 1), 256, 0, stream>>>(
        y1, c_sWif, bm_sf, xw, nullptr, nullptr, nullptr);
    for (int i = 0; i < T; i++)
      hstep<<<c / 16, 256, 0, stream>>>(
          xw + (size_t)i * cX, i ? hf + (size_t)(i - 1) * cH : nullptr,
          hf + (size_t)i * cH, c_sWhf, s_bh_f, c);
    // bi backward
    xw_gemm<<<dim3((T * c / 64) * 12, 1), 256, 0, stream>>>(
        y1, c_sWib, bm_sb, xw, nullptr, nullptr, nullptr);
    for (int i = 0; i < T; i++) {
      int tb = T - 1 - i;
      hstep<<<c / 16, 256, 0, stream>>>(
          xw + (size_t)tb * cX, i ? hb + (size_t)(tb + 1) * cH : nullptr,
          hb + (size_t)tb * cH, c_sWhb, s_bh_b, c);
    }
    sent_tail_part<<<dim3(c / 16, 8), 256, 0, stream>>>(
        hf, hb, s_ln_g, s_ln_b, c_linW, s_linb, part, c);
    tail_reduce<<<c, 256, 0, stream>>>(part, store + (size_t)base * 256, c);
  }

  // ---- document encoder (r12 persistent pgru) ----
  xw_gemm<<<dim3((3072 / 64) * 12, 1), 256, 0, stream>>>(
      store, c_dWiF, bm_dF, xw_u, nullptr, nullptr, nullptr);
  pgru<<<dim3(2, 1), 512, 0, stream>>>(
      xw_u, c_dWhF, dbhF, nullptr, nullptr, nullptr,
      yd1ln, nullptr, 256, d_lnF_g, d_lnF_b, S, 32, 0, 0);
  xw_gemm<<<dim3((3072 / 64) * 12, 2), 256, 0, stream>>>(
      yd1ln, c_dWif, bm_df, xwdf, c_dWib, bm_db, xwdb);
  pgru<<<dim3(2, 2), 512, 0, stream>>>(
      xwdf, c_dWhf, dbh_f, xwdb, c_dWhb, dbh_b,
      ybid, ybid + 256, 512, nullptr, nullptr, S, 32, 0, 1);
  ln_out_head<<<768, 256, 0, stream>>>(ybid, d_ln_g, d_ln_b, out_W, out_b,
                                       (float*)d_out);
}

// Round 16
// 3587.185 us; speedup vs baseline: 2.1860x; 1.7155x over previous
//
#include <hip/hip_runtime.h>

// ---------------------------------------------------------------------------
// SequenceTaggle: hierarchical GRU (sentence enc -> doc enc) on MI355X.
// V=32000 E=256 H=256 O=2 S=96 T=32 B=32, N = S*B = 3072.
// DEVICE DTYPES: float tensors f32; tokens int32; output f32.
// Internal: bf16 MFMA, f32 accumulation.
// pgru (r12-verified): 512 thr = 8 waves; wave owns 32 cols; 82.7 KB LDS;
// xw staged via global_load_lds (triple-buffered), counted vmcnt(3).
// Sentence bi-GRU: if workspace permits, both directions run in ONE pgru
// launch (grid (c/16,2)) with separate xw buffers; else r12 sequential path.
// ---------------------------------------------------------------------------

typedef __bf16 bf16;
typedef __bf16 bf16x8 __attribute__((ext_vector_type(8)));
typedef __bf16 bf16x4 __attribute__((ext_vector_type(4)));
typedef float  f32x4  __attribute__((ext_vector_type(4)));

static __device__ __forceinline__ f32x4 mfma16(bf16x8 a, bf16x8 b, f32x4 c) {
  return __builtin_amdgcn_mfma_f32_16x16x32_bf16(a, b, c, 0, 0, 0);
}
static __device__ __forceinline__ float sigm(float x) { return 1.f / (1.f + __expf(-x)); }
static __device__ __forceinline__ bf16x8 asbf(f32x4 v) {
  union { f32x4 f; bf16x8 b; } u; u.f = v; return u.b;
}
static __device__ __forceinline__ void wg_barrier() {
  asm volatile("s_waitcnt lgkmcnt(0)" ::: "memory");
  __builtin_amdgcn_s_barrier();
  __builtin_amdgcn_sched_barrier(0);
}
static __device__ __forceinline__ void gload16(const bf16* g, bf16* l) {
  __builtin_amdgcn_global_load_lds(
      (const __attribute__((address_space(1))) void*)g,
      (__attribute__((address_space(3))) void*)l, 16, 0, 0);
}

// ---- generic f32 -> bf16 (n4 float4 groups) ----
__global__ __launch_bounds__(256) void cvt_bf16(
    const float* __restrict__ s, bf16* __restrict__ d, int n4)
{
  int i = blockIdx.x * 256 + threadIdx.x;
  if (i < n4) {
    float4 v = ((const float4*)s)[i];
    bf16x4 o;
    o[0] = (bf16)v.x; o[1] = (bf16)v.y; o[2] = (bf16)v.z; o[3] = (bf16)v.w;
    ((bf16x4*)d)[i] = o;
  }
}

// ---- one-shot weight conversion: 12 GRU mats (196608 ea) + linW (131072) ----
__global__ __launch_bounds__(256) void conv13(
    const float* s0, const float* s1, const float* s2, const float* s3,
    const float* s4, const float* s5, const float* s6, const float* s7,
    const float* s8, const float* s9, const float* s10, const float* s11,
    const float* s12, bf16* __restrict__ dst)
{
  const float* srcs[13] = {s0,s1,s2,s3,s4,s5,s6,s7,s8,s9,s10,s11,s12};
  int m = blockIdx.y;
  int n4 = (m == 12) ? 32768 : 49152;
  int i = blockIdx.x * 256 + threadIdx.x;
  if (i >= n4) return;
  float4 v = ((const float4*)srcs[m])[i];
  bf16x4 o;
  o[0] = (bf16)v.x; o[1] = (bf16)v.y; o[2] = (bf16)v.z; o[3] = (bf16)v.w;
  ((bf16x4*)(dst + (size_t)m * 196608))[i] = o;
}

// ---- bmod[g][i] = bi[i] + (i<512 ? bh[i] : 0)  for 6 GRUs. grid (3,6). ----
__global__ __launch_bounds__(256) void prep_bias(
    const float* b0i, const float* b0h, const float* b1i, const float* b1h,
    const float* b2i, const float* b2h, const float* b3i, const float* b3h,
    const float* b4i, const float* b4h, const float* b5i, const float* b5h,
    float* __restrict__ out)
{
  const float* bis[6] = {b0i,b1i,b2i,b3i,b4i,b5i};
  const float* bhs[6] = {b0h,b1h,b2h,b3h,b4h,b5h};
  int g = blockIdx.y;
  int i = blockIdx.x * 256 + threadIdx.x;
  if (i < 768)
    out[g * 768 + i] = bis[g][i] + (i < 512 ? bhs[g][i] : 0.f);
}

// ---------------------------------------------------------------------------
// xw = X(M x 256) @ W(768 x 256)^T + bias -> (M x 768) bf16.
// Wave handles 64 rows x 16 cols. grid.x=(M/64)*12; gridDim.y selects set.
// ---------------------------------------------------------------------------
__global__ __launch_bounds__(256) void xw_gemm(
    const bf16* __restrict__ X,
    const bf16* __restrict__ W0, const float* __restrict__ b0, bf16* __restrict__ o0,
    const bf16* __restrict__ W1, const float* __restrict__ b1, bf16* __restrict__ o1)
{
  const bf16* W = blockIdx.y ? W1 : W0;
  const float* bias = blockIdx.y ? b1 : b0;
  bf16* out = blockIdx.y ? o1 : o0;
  int wave = (int)blockIdx.x * 4 + (threadIdx.x >> 6);
  int g64 = wave / 48, ct = wave - g64 * 48;
  int lane = threadIdx.x & 63;
  int r16 = lane & 15, g4 = lane >> 4;
  const bf16* wp = W + (size_t)(ct * 16 + r16) * 256;
  const bf16* xb = X + ((size_t)g64 * 64 + r16) * 256;
  f32x4 a0 = {0,0,0,0}, a1 = {0,0,0,0}, a2 = {0,0,0,0}, a3 = {0,0,0,0};
#pragma unroll
  for (int kk = 0; kk < 8; kk++) {
    int k0 = kk * 32 + g4 * 8;
    bf16x8 wf = *(const bf16x8*)(wp + k0);
    a0 = mfma16(*(const bf16x8*)(xb + k0), wf, a0);
    a1 = mfma16(*(const bf16x8*)(xb + 4096 + k0), wf, a1);
    a2 = mfma16(*(const bf16x8*)(xb + 8192 + k0), wf, a2);
    a3 = mfma16(*(const bf16x8*)(xb + 12288 + k0), wf, a3);
  }
  float bv = bias[ct * 16 + r16];
#pragma unroll
  for (int rt = 0; rt < 4; rt++) {
    f32x4 ac = rt == 0 ? a0 : rt == 1 ? a1 : rt == 2 ? a2 : a3;
#pragma unroll
    for (int j = 0; j < 4; j++)
      out[(size_t)(g64 * 64 + rt * 16 + g4 * 4 + j) * 768 + ct * 16 + r16] = (bf16)(ac[j] + bv);
  }
}

// ---------------------------------------------------------------------------
// xw1 = emb[tok] @ W^T + bias (gather fused). blockIdx.y = t.
// ---------------------------------------------------------------------------
__global__ __launch_bounds__(256) void xw_gather_gemm(
    const int* __restrict__ tok, const bf16* __restrict__ embb,
    const bf16* __restrict__ W, const float* __restrict__ bias,
    bf16* __restrict__ out, int c)
{
  int t = blockIdx.y;
  int wave = (int)blockIdx.x * 4 + (threadIdx.x >> 6);
  int g64 = wave / 48, ct = wave - g64 * 48;
  int lane = threadIdx.x & 63;
  int r16 = lane & 15, g4 = lane >> 4;
  const bf16* wp = W + (size_t)(ct * 16 + r16) * 256;
  const bf16* ap[4];
#pragma unroll
  for (int rt = 0; rt < 4; rt++) {
    int n = g64 * 64 + rt * 16 + r16;
    int tk = tok[((n >> 5) << 10) + (t << 5) + (n & 31)];
    ap[rt] = embb + (size_t)tk * 256;
  }
  f32x4 a0 = {0,0,0,0}, a1 = {0,0,0,0}, a2 = {0,0,0,0}, a3 = {0,0,0,0};
#pragma unroll
  for (int kk = 0; kk < 8; kk++) {
    int k0 = kk * 32 + g4 * 8;
    bf16x8 wf = *(const bf16x8*)(wp + k0);
    a0 = mfma16(*(const bf16x8*)(ap[0] + k0), wf, a0);
    a1 = mfma16(*(const bf16x8*)(ap[1] + k0), wf, a1);
    a2 = mfma16(*(const bf16x8*)(ap[2] + k0), wf, a2);
    a3 = mfma16(*(const bf16x8*)(ap[3] + k0), wf, a3);
  }
  float bv = bias[ct * 16 + r16];
#pragma unroll
  for (int rt = 0; rt < 4; rt++) {
    f32x4 ac = rt == 0 ? a0 : rt == 1 ? a1 : rt == 2 ? a2 : a3;
#pragma unroll
    for (int j = 0; j < 4; j++)
      out[((size_t)t * c + g64 * 64 + rt * 16 + g4 * 4 + j) * 768 + ct * 16 + r16] = (bf16)(ac[j] + bv);
  }
}

// ---------------------------------------------------------------------------
// Persistent GRU (r12-verified). 512 thr = 8 waves; wave owns 32 cols.
// Static LDS 82.7 KB; xw via global_load_lds, counted vmcnt(3).
// ---------------------------------------------------------------------------
__global__ __launch_bounds__(512)
__attribute__((amdgpu_waves_per_eu(1, 2)))
void pgru(
    const bf16* __restrict__ xw0, const bf16* __restrict__ Wh0, const float* __restrict__ bh0,
    const bf16* __restrict__ xw1, const bf16* __restrict__ Wh1, const float* __restrict__ bh1,
    bf16* __restrict__ yout0, bf16* __restrict__ yout1, int ostride,
    const float* __restrict__ lng, const float* __restrict__ lnb,
    int steps, int Mtot, int rev0, int rev1)
{
  int dir = blockIdx.y;
  const bf16*  xw = dir ? xw1 : xw0;
  const bf16*  Wh = dir ? Wh1 : Wh0;
  const float* bh = dir ? bh1 : bh0;
  bf16* yout = dir ? yout1 : yout0;
  int rev = dir ? rev1 : rev0;

  __shared__ __align__(16) bf16 hbuf[16][280];
  __shared__ __align__(16) bf16 xbuf[3][8][3][16][32];

  int tid = threadIdx.x;
  int w = tid >> 6, lane = tid & 63, r16 = lane & 15, g4 = lane >> 4;
  int rowbase = (int)blockIdx.x * 16;
  int c0 = w * 32 + r16, c1 = c0 + 16;

  for (int i2 = tid; i2 < 560; i2 += 512) ((bf16x8*)hbuf)[i2] = (bf16x8){};

  f32x4 wr0[8], wz0[8], wn0[8], wr1[8], wz1[8], wn1[8];
  {
    const bf16* W0 = Wh + (size_t)c0 * 256;
    const bf16* W1 = Wh + (size_t)c1 * 256;
#pragma unroll
    for (int kk = 0; kk < 8; kk++) {
      int k0 = kk * 32 + g4 * 8;
      wr0[kk] = *(const f32x4*)(W0 + k0);          asm volatile("" : "+v"(wr0[kk]));
      wz0[kk] = *(const f32x4*)(W0 + 65536 + k0);  asm volatile("" : "+v"(wz0[kk]));
      wn0[kk] = *(const f32x4*)(W0 + 131072 + k0); asm volatile("" : "+v"(wn0[kk]));
      wr1[kk] = *(const f32x4*)(W1 + k0);          asm volatile("" : "+v"(wr1[kk]));
      wz1[kk] = *(const f32x4*)(W1 + 65536 + k0);  asm volatile("" : "+v"(wz1[kk]));
      wn1[kk] = *(const f32x4*)(W1 + 131072 + k0); asm volatile("" : "+v"(wn1[kk]));
    }
  }
  float bhn0 = bh[c0 + 512], bhn1 = bh[c1 + 512];

  int m_ = lane >> 2;
  int k_ = (lane & 3) * 8;
  auto stage = [&](int b, int st) {
    const bf16* s = xw + ((size_t)st * Mtot + rowbase + m_) * 768 + w * 32 + k_;
    gload16(s,       &xbuf[b][w][0][0][0]);
    gload16(s + 256, &xbuf[b][w][1][0][0]);
    gload16(s + 512, &xbuf[b][w][2][0][0]);
  };
  stage(0, rev ? steps - 1 : 0);
  wg_barrier();

  for (int i = 0; i < steps; i++) {
    int cur = i % 3;
    int st = rev ? steps - 1 - i : i;
    if (i + 1 < steps) {
      stage((i + 1) % 3, rev ? steps - 2 - i : i + 1);
      asm volatile("s_waitcnt vmcnt(3)" ::: "memory");
    } else {
      asm volatile("s_waitcnt vmcnt(0)" ::: "memory");
    }
    __builtin_amdgcn_sched_barrier(0);

    float hn0[4], hn1[4];
    {
      f32x4 a0 = {0,0,0,0}, a1 = {0,0,0,0}, a2 = {0,0,0,0};
#pragma unroll
      for (int kk = 0; kk < 8; kk++) {
        bf16x8 a = *(const bf16x8*)&hbuf[r16][kk * 32 + g4 * 8];
        a0 = mfma16(a, asbf(wr0[kk]), a0);
        a1 = mfma16(a, asbf(wz0[kk]), a1);
        a2 = mfma16(a, asbf(wn0[kk]), a2);
      }
#pragma unroll
      for (int j = 0; j < 4; j++) {
        int m = g4 * 4 + j;
        float r = sigm((float)xbuf[cur][w][0][m][r16] + a0[j]);
        float z = sigm((float)xbuf[cur][w][1][m][r16] + a1[j]);
        float n = tanhf((float)xbuf[cur][w][2][m][r16] + r * (a2[j] + bhn0));
        hn0[j] = (1.f - z) * n + z * (float)hbuf[m][c0];
      }
    }
    {
      f32x4 a0 = {0,0,0,0}, a1 = {0,0,0,0}, a2 = {0,0,0,0};
#pragma unroll
      for (int kk = 0; kk < 8; kk++) {
        bf16x8 a = *(const bf16x8*)&hbuf[r16][kk * 32 + g4 * 8];
        a0 = mfma16(a, asbf(wr1[kk]), a0);
        a1 = mfma16(a, asbf(wz1[kk]), a1);
        a2 = mfma16(a, asbf(wn1[kk]), a2);
      }
#pragma unroll
      for (int j = 0; j < 4; j++) {
        int m = g4 * 4 + j;
        float r = sigm((float)xbuf[cur][w][0][m][r16 + 16] + a0[j]);
        float z = sigm((float)xbuf[cur][w][1][m][r16 + 16] + a1[j]);
        float n = tanhf((float)xbuf[cur][w][2][m][r16 + 16] + r * (a2[j] + bhn1));
        hn1[j] = (1.f - z) * n + z * (float)hbuf[m][c1];
      }
    }
    wg_barrier();
#pragma unroll
    for (int j = 0; j < 4; j++) {
      int m = g4 * 4 + j;
      hbuf[m][c0] = (bf16)hn0[j];
      hbuf[m][c1] = (bf16)hn1[j];
    }
    if (!lng) {
#pragma unroll
      for (int j = 0; j < 4; j++) {
        size_t ro = ((size_t)st * Mtot + rowbase + g4 * 4 + j) * ostride;
        yout[ro + c0] = (bf16)hn0[j];
        yout[ro + c1] = (bf16)hn1[j];
      }
    }
    wg_barrier();
    if (lng) {
#pragma unroll
      for (int rr = 0; rr < 2; rr++) {
        int r = w * 2 + rr;
        bf16x4 v4 = *(const bf16x4*)&hbuf[r][lane * 4];
        float v[4]; float sm = 0.f, sq = 0.f;
#pragma unroll
        for (int j = 0; j < 4; j++) { v[j] = (float)v4[j]; sm += v[j]; sq += v[j] * v[j]; }
        for (int msk = 32; msk; msk >>= 1) { sm += __shfl_xor(sm, msk); sq += __shfl_xor(sq, msk); }
        float mu  = sm * (1.f / 256.f);
        float var = sq * (1.f / 256.f) - mu * mu;
        float inv = rsqrtf(fmaxf(var, 0.f) + 1e-5f);
        bf16x4 o;
#pragma unroll
        for (int j = 0; j < 4; j++)
          o[j] = (bf16)((v[j] - mu) * inv * lng[lane * 4 + j] + lnb[lane * 4 + j]);
        *(bf16x4*)&yout[((size_t)st * Mtot + rowbase + r) * ostride + lane * 4] = o;
      }
    }
  }
}

// ---------------------------------------------------------------------------
// Sentence tail, t-parallel: block (r-tile, tg) accumulates 4 t's of
// tanh(LN512(hf||hb) @ linW^T + b) into part[tg] (f32). grid (c/16, 8).
// ---------------------------------------------------------------------------
__global__ __launch_bounds__(256) void sent_tail_part(
    const bf16* __restrict__ hf, const bf16* __restrict__ hb,
    const float* __restrict__ gam, const float* __restrict__ bet,
    const bf16* __restrict__ W, const float* __restrict__ bias,
    float* __restrict__ part, int c)
{
  int wave = threadIdx.x >> 6;
  int lane = threadIdx.x & 63;
  int r16 = lane & 15, g4 = lane >> 4;
  int r0 = (int)blockIdx.x << 4;
  int tg = blockIdx.y;
  size_t rowoff = (size_t)(r0 + r16) * 256;

  f32x4 ms0 = {0,0,0,0}, ms1 = {0,0,0,0}, ms2 = {0,0,0,0}, ms3 = {0,0,0,0};

  for (int tt = 0; tt < 4; tt++) {
    int t = tg * 4 + tt;
    const bf16* pf = hf + (size_t)t * c * 256 + rowoff;
    const bf16* pb = hb + (size_t)t * c * 256 + rowoff;
    bf16x8 xv[16];
    float s = 0.f, sq = 0.f;
#pragma unroll
    for (int kk = 0; kk < 16; kk++) {
      int k0 = kk * 32 + g4 * 8;
      xv[kk] = (kk < 8) ? *(const bf16x8*)(pf + k0) : *(const bf16x8*)(pb + k0 - 256);
#pragma unroll
      for (int j = 0; j < 8; j++) { float f = (float)xv[kk][j]; s += f; sq += f * f; }
    }
    s  += __shfl_xor(s, 16);  s  += __shfl_xor(s, 32);
    sq += __shfl_xor(sq, 16); sq += __shfl_xor(sq, 32);
    float mu  = s * (1.f / 512.f);
    float var = sq * (1.f / 512.f) - mu * mu;
    float inv = rsqrtf(fmaxf(var, 0.f) + 1e-5f);
#pragma unroll
    for (int kk = 0; kk < 16; kk++) {
      int k0 = kk * 32 + g4 * 8;
      float ga[8], be[8];
      *(float4*)(ga)     = *(const float4*)(gam + k0);
      *(float4*)(ga + 4) = *(const float4*)(gam + k0 + 4);
      *(float4*)(be)     = *(const float4*)(bet + k0);
      *(float4*)(be + 4) = *(const float4*)(bet + k0 + 4);
#pragma unroll
      for (int j = 0; j < 8; j++)
        xv[kk][j] = (bf16)(((float)xv[kk][j] - mu) * inv * ga[j] + be[j]);
    }
#pragma unroll
    for (int tc = 0; tc < 4; tc++) {
      int cj = wave * 64 + tc * 16;
      const bf16* wp = W + (size_t)(cj + r16) * 512;
      f32x4 acc = {0,0,0,0};
#pragma unroll
      for (int kk = 0; kk < 16; kk++)
        acc = mfma16(xv[kk], *(const bf16x8*)(wp + kk * 32 + g4 * 8), acc);
      float bb = bias[cj + r16];
      f32x4* msp = (tc == 0) ? &ms0 : (tc == 1) ? &ms1 : (tc == 2) ? &ms2 : &ms3;
#pragma unroll
      for (int j = 0; j < 4; j++) (*msp)[j] += tanhf(acc[j] + bb);
    }
  }
#pragma unroll
  for (int tc = 0; tc < 4; tc++) {
    int cj = wave * 64 + tc * 16;
    f32x4 ms = (tc == 0) ? ms0 : (tc == 1) ? ms1 : (tc == 2) ? ms2 : ms3;
#pragma unroll
    for (int j = 0; j < 4; j++)
      part[((size_t)tg * c + r0 + g4 * 4 + j) * 256 + cj + r16] = ms[j];
  }
}

// sum 8 partials, scale 1/32, write bf16. grid = c blocks x 256 thr.
__global__ __launch_bounds__(256) void tail_reduce(
    const float* __restrict__ part, bf16* __restrict__ out, int c)
{
  int idx = blockIdx.x * 256 + threadIdx.x;
  float s = 0.f;
#pragma unroll
  for (int g = 0; g < 8; g++) s += part[(size_t)g * c * 256 + idx];
  out[idx] = (bf16)(s * 0.03125f);
}

// ---------------------------------------------------------------------------
// Fused LN(512) + sigmoid head: out(3072x2 f32). Wave per row.
// ---------------------------------------------------------------------------
__global__ __launch_bounds__(256) void ln_out_head(
    const bf16* __restrict__ X, const float* __restrict__ lng, const float* __restrict__ lnb,
    const float* __restrict__ W, const float* __restrict__ bias, float* __restrict__ out)
{
  int w = threadIdx.x >> 6, lane = threadIdx.x & 63;
  int row = (int)blockIdx.x * 4 + w;
  bf16x8 v8 = *(const bf16x8*)&X[(size_t)row * 512 + lane * 8];
  float v[8]; float sm = 0.f, sq = 0.f;
#pragma unroll
  for (int j = 0; j < 8; j++) { v[j] = (float)v8[j]; sm += v[j]; sq += v[j] * v[j]; }
  for (int msk = 32; msk; msk >>= 1) { sm += __shfl_xor(sm, msk); sq += __shfl_xor(sq, msk); }
  float mu  = sm * (1.f / 512.f);
  float var = sq * (1.f / 512.f) - mu * mu;
  float inv = rsqrtf(fmaxf(var, 0.f) + 1e-5f);
  float a0 = 0.f, a1 = 0.f;
  int base = lane * 8;
#pragma unroll
  for (int j = 0; j < 8; j++) {
    float y = (v[j] - mu) * inv * lng[base + j] + lnb[base + j];
    a0 += y * W[base + j];
    a1 += y * W[512 + base + j];
  }
  for (int msk = 32; msk; msk >>= 1) { a0 += __shfl_xor(a0, msk); a1 += __shfl_xor(a1, msk); }
  if (lane == 0) {
    out[(size_t)row * 2 + 0] = sigm(a0 + bias[0]);
    out[(size_t)row * 2 + 1] = sigm(a1 + bias[1]);
  }
}

// ---------------------------------------------------------------------------
extern "C" void kernel_launch(void* const* d_in, const int* in_sizes, int n_in,
                              void* d_out, int out_size, void* d_ws, size_t ws_size,
                              hipStream_t stream)
{
  (void)in_sizes; (void)n_in; (void)out_size;
  const int*   tokens = (const int*)d_in[0];
  const float* emb    = (const float*)d_in[1];
  auto fp = [&](int i) { return (const float*)d_in[i]; };
  const float *s_WiF = fp(2),  *s_WhF = fp(3),  *s_biF = fp(4),  *s_bhF = fp(5);
  const float *s_lnF_g = fp(6), *s_lnF_b = fp(7);
  const float *s_Wi_f = fp(8),  *s_Wh_f = fp(9),  *s_bi_f = fp(10), *s_bh_f = fp(11);
  const float *s_Wi_b = fp(12), *s_Wh_b = fp(13), *s_bi_b = fp(14), *s_bh_b = fp(15);
  const float *s_ln_g = fp(16), *s_ln_b = fp(17), *s_linW = fp(18), *s_linb = fp(19);
  const float *dWiF = fp(20), *dWhF = fp(21), *dbiF = fp(22), *dbhF = fp(23);
  const float *d_lnF_g = fp(24), *d_lnF_b = fp(25);
  const float *dWi_f = fp(26), *dWh_f = fp(27), *dbi_f = fp(28), *dbh_f = fp(29);
  const float *dWi_b = fp(30), *dWh_b = fp(31), *dbi_b = fp(32), *dbh_b = fp(33);
  const float *d_ln_g = fp(34), *d_ln_b = fp(35), *out_W = fp(36), *out_b = fp(37);

  const int T = 32, S = 96;
  const int GW = 196608;

  // ---- converted bf16 weights + emb + folded biases ----
  bf16* wc = (bf16*)d_ws;
  bf16 *c_sWiF = wc,         *c_sWhF = wc + GW;
  bf16 *c_sWif = wc + 2*GW,  *c_sWhf = wc + 3*GW;
  bf16 *c_sWib = wc + 4*GW,  *c_sWhb = wc + 5*GW;
  bf16 *c_dWiF = wc + 6*GW,  *c_dWhF = wc + 7*GW;
  bf16 *c_dWif = wc + 8*GW,  *c_dWhf = wc + 9*GW;
  bf16 *c_dWib = wc + 10*GW, *c_dWhb = wc + 11*GW;
  bf16 *c_linW = wc + 12*GW;
  const size_t WB = (size_t)(12 * GW + 131072) * 2;       // 4,980,736
  bf16* embb = (bf16*)((char*)d_ws + WB);                 // 32000x256 bf16
  const size_t EB = (size_t)32000 * 256 * 2;              // 16,384,000
  float* bmod = (float*)((char*)d_ws + WB + EB);          // 6 x 768 f32
  const size_t BMB = 6 * 768 * 4;                         // 18,432

  conv13<<<dim3(192, 13), 256, 0, stream>>>(
      s_WiF, s_WhF, s_Wi_f, s_Wh_f, s_Wi_b, s_Wh_b,
      dWiF, dWhF, dWi_f, dWh_f, dWi_b, dWh_b, s_linW, wc);
  cvt_bf16<<<8000, 256, 0, stream>>>(emb, embb, 2048000);
  prep_bias<<<dim3(3, 6), 256, 0, stream>>>(
      s_biF, s_bhF, s_bi_f, s_bh_f, s_bi_b, s_bh_b,
      dbiF, dbhF, dbi_f, dbh_f, dbi_b, dbh_b, bmod);
  const float *bm_sF = bmod, *bm_sf = bmod + 768, *bm_sb = bmod + 1536;
  const float *bm_dF = bmod + 2304, *bm_df = bmod + 3072, *bm_db = bmod + 3840;

  // ---- fixed doc-side buffers ----
  char* ws = (char*)d_ws + WB + EB + BMB;
  bf16* store = (bf16*)ws;                           // (3072, 256)
  bf16* yd1ln = store + (size_t)3072 * 256;          // (3072, 256)
  bf16* ybid  = yd1ln + (size_t)3072 * 256;          // (3072, 512)
  bf16* xw_u  = ybid  + (size_t)3072 * 512;          // (3072, 768)
  bf16* xwdf  = xw_u  + (size_t)3072 * 768;
  bf16* xwdb  = xwdf  + (size_t)3072 * 768;
  const size_t fixedB = WB + EB + BMB
      + ((size_t)3072 * 256 * 2 + (size_t)3072 * 512 + (size_t)3 * 3072 * 768) * 2;

  // ---- sentence layout: dual-xw (bi dirs in one launch) if ws permits ----
  // dual per-row: xwf 49152 + xwb 49152 + y1ln 16384 + hf 16384 + hb 16384
  bool dual = (fixedB + (size_t)147456 * 3072 <= ws_size);
  int c = 3072;
  if (!dual) {
    while (c > 192 && fixedB + (size_t)98304 * c > ws_size) c >>= 1;
  }
  char* cb = (char*)d_ws + fixedB;
  bf16 *xwf, *xwb, *y1ln, *hf, *hb;
  float* part;
  if (dual) {
    xwf  = (bf16*)cb;                                // (T*c, 768)
    xwb  = (bf16*)(cb + (size_t)49152 * c);          // (T*c, 768)
    y1ln = (bf16*)(cb + (size_t)98304 * c);          // (T*c, 256)
    hf   = (bf16*)(cb + (size_t)114688 * c);         // (T*c, 256)
    hb   = (bf16*)(cb + (size_t)131072 * c);         // (T*c, 256)
    part = (float*)cb;                               // aliases xwf (free by then)
  } else {
    xwf  = (bf16*)cb;                                // (T*c, 768), reused 3x
    xwb  = xwf;
    y1ln = (bf16*)(cb + (size_t)49152 * c);
    hf   = (bf16*)(cb + (size_t)65536 * c);
    hb   = (bf16*)(cb + (size_t)81920 * c);
    part = (float*)cb;
  }

  // ---- sentence encoder, chunked ----
  for (int base = 0; base < 3072; base += c) {
    const int* tkb = tokens + (size_t)base * 32;
    // GRU1: x-projection (emb gather fused) into xwf, recurrence + fused LN
    xw_gather_gemm<<<dim3((c / 64) * 12, T), 256, 0, stream>>>(
        tkb, embb, c_sWiF, bm_sF, xwf, c);
    pgru<<<dim3(c / 16, 1), 512, 0, stream>>>(
        xwf, c_sWhF, s_bhF, nullptr, nullptr, nullptr,
        y1ln, nullptr, 256, s_lnF_g, s_lnF_b, T, c, 0, 0);
    if (dual) {
      // both bi x-projections, then BOTH directions in one pgru launch
      xw_gemm<<<dim3((T * c / 64) * 12, 2), 256, 0, stream>>>(
          y1ln, c_sWif, bm_sf, xwf, c_sWib, bm_sb, xwb);
      pgru<<<dim3(c / 16, 2), 512, 0, stream>>>(
          xwf, c_sWhf, s_bh_f, xwb, c_sWhb, s_bh_b,
          hf, hb, 256, nullptr, nullptr, T, c, 0, 1);
    } else {
      xw_gemm<<<dim3((T * c / 64) * 12, 1), 256, 0, stream>>>(
          y1ln, c_sWif, bm_sf, xwf, nullptr, nullptr, nullptr);
      pgru<<<dim3(c / 16, 1), 512, 0, stream>>>(
          xwf, c_sWhf, s_bh_f, nullptr, nullptr, nullptr,
          hf, nullptr, 256, nullptr, nullptr, T, c, 0, 0);
      xw_gemm<<<dim3((T * c / 64) * 12, 1), 256, 0, stream>>>(
          y1ln, c_sWib, bm_sb, xwf, nullptr, nullptr, nullptr);
      pgru<<<dim3(c / 16, 1), 512, 0, stream>>>(
          xwf, c_sWhb, s_bh_b, nullptr, nullptr, nullptr,
          hb, nullptr, 256, nullptr, nullptr, T, c, 1, 0);
    }
    sent_tail_part<<<dim3(c / 16, 8), 256, 0, stream>>>(
        hf, hb, s_ln_g, s_ln_b, c_linW, s_linb, part, c);
    tail_reduce<<<c, 256, 0, stream>>>(part, store + (size_t)base * 256, c);
  }

  // ---- document encoder ----
  xw_gemm<<<dim3((3072 / 64) * 12, 1), 256, 0, stream>>>(
      store, c_dWiF, bm_dF, xw_u, nullptr, nullptr, nullptr);
  pgru<<<dim3(2, 1), 512, 0, stream>>>(
      xw_u, c_dWhF, dbhF, nullptr, nullptr, nullptr,
      yd1ln, nullptr, 256, d_lnF_g, d_lnF_b, S, 32, 0, 0);
  xw_gemm<<<dim3((3072 / 64) * 12, 2), 256, 0, stream>>>(
      yd1ln, c_dWif, bm_df, xwdf, c_dWib, bm_db, xwdb);
  pgru<<<dim3(2, 2), 512, 0, stream>>>(
      xwdf, c_dWhf, dbh_f, xwdb, c_dWhb, dbh_b,
      ybid, ybid + 256, 512, nullptr, nullptr, S, 32, 0, 1);
  ln_out_head<<<768, 256, 0, stream>>>(ybid, d_ln_g, d_ln_b, out_W, out_b,
                                       (float*)d_out);
}